// Round 4
// baseline (1276.871 us; speedup 1.0000x reference)
//
#include <hip/hip_runtime.h>

// ConvLstm (B=64, S=256, H=1024, fp32 in/out) — fused persistent kernel, round 10.
//
// Round-9 post-mortem: 4.38 us/step. VALUBusy 17% ~= 13 poll iterations/step;
// each iteration re-loads the wave's 8 KiB slice => ~100 MB/step of UC poll
// traffic (~24 TB/s) saturating the LLC fabric — the poll delays the very
// stores it waits for (R6's tiny-poll crossings cost ~1.8 us; R9's single
// crossing ~3.6 us => congestion, not intrinsic latency).
//
// Round-10: HINT-GATED CONSUME — poll 64 B, not 8 KiB.
//  * hints[4clusters][64slots] uint in ws: producer stores tag t+1 (UC dword)
//    right after its 32 data-chunk pushes. UNORDERED vs data (no ack) —
//    hints are advisory only.
//  * Consumer wave first polls its 16 producer hints (one 64 B coalesced
//    UC load/iter, s_sleep(8) backoff) until all >= t, THEN runs the
//    sentinel-checked 8 KiB data load (the unchanged correctness gate) —
//    normally exactly once; loops only in the tiny hint-races-data window.
//  * Refill stores moved after stage_write (off the peak store moment).
// All R8/R9 safety proofs unchanged: depth-4 rotation; refill(t, slot
// (t-2)%4) is acked by the owner's step-t+1 poll vmcnt(0) before its h_{t+1}
// push; consumer sees h_{t-2} (sentinel check) => owner's refill of slot
// (t-1)%4 already visible => step-t read sees sentinel or fresh h_{t-1},
// never h_{t-5}. Hint poll only adds an EARLIER vmcnt(0) drain point.
//
// ws layout: [0, 512KiB) fp16 hbuf[4][64][1024] (sentinel-filled);
//            [512KiB, +1KiB) uint hints[4][64] (zeroed).

#define S_LEN 256
#define H_DIM 1024
#define B_DIM 64
#define SENT 0x7FFF7FFFu
#define XROW 1042                              // fp16 elems per ldsx row (stride)

typedef _Float16 v8h __attribute__((ext_vector_type(8)));
typedef float v4f __attribute__((ext_vector_type(4)));
typedef unsigned v4u __attribute__((ext_vector_type(4)));

__device__ __forceinline__ v8h pack8h(float4 a, float4 b) {
  v8h r;
  r[0] = (_Float16)a.x; r[1] = (_Float16)a.y; r[2] = (_Float16)a.z; r[3] = (_Float16)a.w;
  r[4] = (_Float16)b.x; r[5] = (_Float16)b.y; r[6] = (_Float16)b.z; r[7] = (_Float16)b.w;
  return r;
}

__device__ __forceinline__ float fsigmoid(float x) { return 1.0f / (1.0f + __expf(-x)); }
__device__ __forceinline__ float ftanh(float x) {
  float e = __expf(2.0f * x);          // +inf for large x is fine: 2/(inf+1)=0
  return 1.0f - 2.0f / (e + 1.0f);
}

__global__ void k_init(unsigned* __restrict__ hb, unsigned* __restrict__ hints) {
  int i = blockIdx.x * 256 + threadIdx.x;
  for (int idx = i; idx < 4 * B_DIM * H_DIM / 2; idx += gridDim.x * 256)
    hb[idx] = SENT;
  if (i < 256) hints[i] = 0u;
}

__global__ __launch_bounds__(256, 1) void lstm_fused(
    const float* __restrict__ x, const float* __restrict__ Wx,
    const float* __restrict__ Wh, const float* __restrict__ h0,
    const float* __restrict__ c0, const float* __restrict__ bx,
    const float* __restrict__ bh, const float* __restrict__ bgate,
    const float* __restrict__ peep, float* __restrict__ out,
    _Float16* __restrict__ hbuf, unsigned* __restrict__ hints) {
  __shared__ float pre[4][4][16][18];          // pad 18: store pattern 2-way (free)
  __shared__ _Float16 ldsx[2][16 * XROW];      // double-buffered x tiles
  __shared__ _Float16 hstage[16][16];          // gate-phase h staging for repack

  const int tid = threadIdx.x;
  const int wid = tid >> 6;                    // wave id = K-range owner
  const int lane = tid & 63;
  const int la = lane & 15;                    // MFMA: A-row (batch) / B-col (chan)
  const int lq = lane >> 4;
  const int cluster = blockIdx.x >> 6;         // 4 clusters x 64 WGs
  const int slot = blockIdx.x & 63;
  const int ch0 = slot * 16;                   // this WG's channel slice
  const int b0 = cluster * 16;                 // this cluster's batch slice

  // ---- one-time: weight fragments into VGPRs (fp16 B-operand layout:
  // lane holds B[k = lq*8 + j][n = la]; MFMA kk covers k in [kk*32, kk*32+32)) ----
  v8h wh_f[4][8], wx_f[4][8];
  {
    const int col = wid * 256 + lq * 8;
#pragma unroll
    for (int g = 0; g < 4; ++g) {
#pragma unroll
      for (int kk = 0; kk < 8; ++kk) {
        const float* ph = Wh + (size_t)(g * 1024 + ch0 + la) * 1024 + col + kk * 32;
        wh_f[g][kk] = pack8h(*(const float4*)ph, *(const float4*)(ph + 4));
        const float* px = Wx + (size_t)(g * 1024 + ch0 + la) * 1024 + col + kk * 32;
        wx_f[g][kk] = pack8h(*(const float4*)px, *(const float4*)(px + 4));
      }
    }
  }

  // ---- elementwise-thread constants (thread <-> (batch bl, chan nn)) ----
  const int bl = tid >> 4;
  const int nn = tid & 15;
  const int gb = b0 + bl;                      // global batch
  const int ch = ch0 + nn;                     // global channel
  float bias_c[4];
#pragma unroll
  for (int g = 0; g < 4; ++g)
    bias_c[g] = bx[g * 1024 + ch] + bh[g * 1024 + ch] + bgate[g * 1024 + ch];
  const float pI = peep[ch], pF = peep[1024 + ch], pO = peep[2048 + ch];
  float c_st = c0[gb * 1024 + ch];             // cell state lives in a register

  // ---- x staging, split into early load (regs) + late pack/write (LDS) ----
  float4 sreg[16];
  auto stage_load = [&](int ts) {              // issue 16 float4 loads, no wait
#pragma unroll
    for (int j = 0; j < 8; ++j) {
      int cid = tid + j * 256;                 // 2048 chunks of 8 floats
      int row = cid >> 7, c8 = cid & 127;
      const float* px = x + (size_t)(b0 + row) * (S_LEN * H_DIM) + (size_t)ts * H_DIM + c8 * 8;
      sreg[2 * j] = *(const float4*)px;
      sreg[2 * j + 1] = *(const float4*)(px + 4);
    }
  };
  auto stage_write = [&](int buf) {            // pack + LDS write (waits loads)
#pragma unroll
    for (int j = 0; j < 8; ++j) {
      int cid = tid + j * 256;
      int row = cid >> 7, c8 = cid & 127;
      *(v8h*)(&ldsx[buf][row * XROW + c8 * 8]) = pack8h(sreg[2 * j], sreg[2 * j + 1]);
    }
  };
  const v4f vzero = {0.f, 0.f, 0.f, 0.f};
  v4f acc[4];
  auto xmfma = [&](int buf) {                  // 32 x-side MFMAs from ldsx[buf]
#pragma unroll
    for (int kk = 0; kk < 8; ++kk) {
      v8h ax = *(const v8h*)(&ldsx[buf][la * XROW + wid * 256 + kk * 32 + lq * 8]);
#pragma unroll
      for (int g = 0; g < 4; ++g)
        acc[g] = __builtin_amdgcn_mfma_f32_16x16x32_f16(ax, wx_f[g][kk], acc[g], 0, 0, 0);
    }
  };

  // ---- prologue: x[0] -> buf0, x-partials for step 0, x[1] -> buf1 ----
  stage_load(0); stage_write(0);
  __syncthreads();
#pragma unroll
  for (int g = 0; g < 4; ++g) acc[g] = vzero;
  xmfma(0);
  stage_load(1); stage_write(1);               // buf1: no readers until t=0 tail

  for (int t = 0; t < S_LEN; ++t) {
    // acc holds x-side partials for step t. Get h_{t-1} A-fragments.
    v8h ah[8];
    if (t == 0) {
      const float* hrow = h0 + (size_t)(b0 + la) * H_DIM + wid * 256 + lq * 8;
#pragma unroll
      for (int kk = 0; kk < 8; ++kk)
        ah[kk] = pack8h(*(const float4*)(hrow + kk * 32),
                        *(const float4*)(hrow + kk * 32 + 4));
    } else {
      // (1) hint gate: 64 B coalesced poll of this wave's 16 producers
      // (slots 16*wid .. 16*wid+15). Advisory only — tiny fabric footprint.
      {
        const unsigned* hintp = hints + cluster * 64 + wid * 16 + la;
        const unsigned tgt = (unsigned)t;      // tag t means h_{t-1} pushed
        unsigned hv;
        for (;;) {
          asm volatile(
              "global_load_dword %0, %[p], off sc0 sc1\n\t"
              "s_waitcnt vmcnt(0)"
              : "=v"(hv) : [p] "v"(hintp) : "memory");
          if (__all((int)(hv >= tgt))) break;
          __builtin_amdgcn_s_sleep(8);
        }
      }
      // (2) correctness gate (unchanged): sentinel-checked UC load of the
      // wave's 8 KiB slice of slot (t-1)%4 — normally exactly one pass now.
      const _Float16* hb = hbuf + ((t - 1) & 3) * (B_DIM * H_DIM) +
                           (size_t)(b0 + la) * H_DIM + wid * 256 + lq * 8;
      v4u u0, u1, u2, u3, u4, u5, u6, u7;
      for (;;) {
        asm volatile(
            "global_load_dwordx4 %0, %[p], off sc0 sc1\n\t"
            "global_load_dwordx4 %1, %[p], off offset:64 sc0 sc1\n\t"
            "global_load_dwordx4 %2, %[p], off offset:128 sc0 sc1\n\t"
            "global_load_dwordx4 %3, %[p], off offset:192 sc0 sc1\n\t"
            "global_load_dwordx4 %4, %[p], off offset:256 sc0 sc1\n\t"
            "global_load_dwordx4 %5, %[p], off offset:320 sc0 sc1\n\t"
            "global_load_dwordx4 %6, %[p], off offset:384 sc0 sc1\n\t"
            "global_load_dwordx4 %7, %[p], off offset:448 sc0 sc1\n\t"
            "s_waitcnt vmcnt(0)"
            : "=&v"(u0), "=&v"(u1), "=&v"(u2), "=&v"(u3),
              "=&v"(u4), "=&v"(u5), "=&v"(u6), "=&v"(u7)
            : [p] "v"(hb)
            : "memory");
        int ok = (u0[0] != SENT) & (u0[1] != SENT) & (u0[2] != SENT) & (u0[3] != SENT) &
                 (u1[0] != SENT) & (u1[1] != SENT) & (u1[2] != SENT) & (u1[3] != SENT) &
                 (u2[0] != SENT) & (u2[1] != SENT) & (u2[2] != SENT) & (u2[3] != SENT) &
                 (u3[0] != SENT) & (u3[1] != SENT) & (u3[2] != SENT) & (u3[3] != SENT) &
                 (u4[0] != SENT) & (u4[1] != SENT) & (u4[2] != SENT) & (u4[3] != SENT) &
                 (u5[0] != SENT) & (u5[1] != SENT) & (u5[2] != SENT) & (u5[3] != SENT) &
                 (u6[0] != SENT) & (u6[1] != SENT) & (u6[2] != SENT) & (u6[3] != SENT) &
                 (u7[0] != SENT) & (u7[1] != SENT) & (u7[2] != SENT) & (u7[3] != SENT);
        if (__all(ok)) break;
        __builtin_amdgcn_s_sleep(2);
      }
      ah[0] = __builtin_bit_cast(v8h, u0); ah[1] = __builtin_bit_cast(v8h, u1);
      ah[2] = __builtin_bit_cast(v8h, u2); ah[3] = __builtin_bit_cast(v8h, u3);
      ah[4] = __builtin_bit_cast(v8h, u4); ah[5] = __builtin_bit_cast(v8h, u5);
      ah[6] = __builtin_bit_cast(v8h, u6); ah[7] = __builtin_bit_cast(v8h, u7);
    }
#pragma unroll
    for (int kk = 0; kk < 8; ++kk) {
#pragma unroll
      for (int g = 0; g < 4; ++g)
        acc[g] = __builtin_amdgcn_mfma_f32_16x16x32_f16(ah[kk], wh_f[g][kk], acc[g], 0, 0, 0);
    }

    // publish wave partials: D layout col=lane&15, row=(lane>>4)*4+reg
#pragma unroll
    for (int g = 0; g < 4; ++g)
#pragma unroll
      for (int r = 0; r < 4; ++r)
        pre[wid][g][lq * 4 + r][la] = acc[g][r];
    __syncthreads();                           // sync1: pre ready

    // off-chain: issue next x-tile loads NOW; they drain under gates/push.
    if (t < S_LEN - 2) stage_load(t + 2);

    // elementwise gates (thread = one (batch, channel))
    float s[4];
#pragma unroll
    for (int g = 0; g < 4; ++g)
      s[g] = pre[0][g][bl][nn] + pre[1][g][bl][nn] + pre[2][g][bl][nn] +
             pre[3][g][bl][nn] + bias_c[g];
    float ig = fsigmoid(s[0] + pI * c_st);
    float fg = fsigmoid(s[1] + pF * c_st);
    float cn = fg * c_st + ig + ftanh(s[2]);   // NOTE: +ig (reference quirk), not ig*tanh
    float og = fsigmoid(s[3] + pO * cn);
    float hn = og * ftanh(cn);
    c_st = cn;

    hstage[bl][nn] = (_Float16)hn;             // fp16 h for the packed push
    out[((size_t)gb * S_LEN + t) * H_DIM + ch] = hn;  // cached fp32 out
    __syncthreads();                           // sync2: hstage ready

    if (t < S_LEN - 1) {
      // push this WG's 512 B h-slice (32 lanes x 16B) to slot t%4, then the
      // advisory hint tag. Refill of slot (t-2)%4 is issued later (after
      // stage_write); its ack is the step-t+1 poll's vmcnt(0), which precedes
      // the same-address push at t+2 (same proof as round 8/9).
      if (tid < 32) {
        const int b = tid >> 1, half = tid & 1;
        v4u d = *(const v4u*)(&hstage[b][half * 8]);
        _Float16* hp = hbuf + (t & 3) * (B_DIM * H_DIM) +
                       (size_t)(b0 + b) * H_DIM + ch0 + half * 8;
        asm volatile("global_store_dwordx4 %[p], %[d], off sc0 sc1"
                     :: [p] "v"(hp), [d] "v"(d) : "memory");
      }
      if (tid == 0) {
        unsigned tag = (unsigned)(t + 1);      // advisory: "h_t pushed"
        unsigned* hq = hints + cluster * 64 + slot;
        asm volatile("global_store_dword %[p], %[d], off sc0 sc1"
                     :: [p] "v"(hq), [d] "v"(tag) : "memory");
      }
      // off the chain, behind the push: x-partials for step t+1, then the
      // LDS-write half of staging x[t+2] into buf[t&1] (WAR covered by
      // collective sync2(t)), then the sentinel refill.
#pragma unroll
      for (int g = 0; g < 4; ++g) acc[g] = vzero;
      xmfma((t + 1) & 1);                      // reads buf[(t+1)&1] == x[t+1]
      if (t < S_LEN - 2) stage_write(t & 1);   // buf[t&1] <- x[t+2]
      if (tid < 32 && t >= 2) {
        const int b = tid >> 1, half = tid & 1;
        v4u sv = {SENT, SENT, SENT, SENT};
        _Float16* rp = hbuf + ((t - 2) & 3) * (B_DIM * H_DIM) +
                       (size_t)(b0 + b) * H_DIM + ch0 + half * 8;
        asm volatile("global_store_dwordx4 %[p], %[d], off sc0 sc1"
                     :: [p] "v"(rp), [d] "v"(sv) : "memory");
      }
    }
  }
}

extern "C" void kernel_launch(void* const* d_in, const int* in_sizes, int n_in,
                              void* d_out, int out_size, void* d_ws, size_t ws_size,
                              hipStream_t stream) {
  (void)in_sizes; (void)n_in; (void)out_size; (void)ws_size;
  const float* x    = (const float*)d_in[0];
  const float* h0   = (const float*)d_in[1];
  const float* c0   = (const float*)d_in[2];
  const float* Wx   = (const float*)d_in[3];
  const float* bx   = (const float*)d_in[4];
  const float* Wh   = (const float*)d_in[5];
  const float* bh   = (const float*)d_in[6];
  const float* peep = (const float*)d_in[7];
  const float* bg   = (const float*)d_in[8];
  float* out = (float*)d_out;

  _Float16* hbuf = (_Float16*)d_ws;            // [4][64][1024] fp16 = 512 KiB
  unsigned* hints = (unsigned*)((char*)d_ws + 4 * B_DIM * H_DIM * 2);

  k_init<<<64, 256, 0, stream>>>((unsigned*)d_ws, hints);
  lstm_fused<<<256, 256, 0, stream>>>(x, Wx, Wh, h0, c0, bx, bh, bg, peep,
                                      out, hbuf, hints);
}